// Round 14
// baseline (295.467 us; speedup 1.0000x reference)
//
#include <hip/hip_runtime.h>
#include <hip/hip_bf16.h>
#include <cstdint>
#include <cstddef>

typedef __hip_bfloat16 bf16;
typedef __attribute__((ext_vector_type(8))) short s16x8;
typedef __attribute__((ext_vector_type(4))) float f32x4;

#define MAXN 100
#define HH   4
#define FIN  128
#define KS1  25

static inline int ceil_div(int a, int b){ return (a + b - 1) / b; }

__device__ inline short f2bf(float f){               // RNE float->bf16 bits
  unsigned int u = __float_as_uint(f);
  u = (u + 0x7FFF + ((u >> 16) & 1)) >> 16;
  return (short)u;
}
__device__ inline float loadf(const void* s, int i, bool isbf){
  return isbf ? __bfloat162float(((const bf16*)s)[i]) : ((const float*)s)[i];
}

// ---------------- input dtype sniff ----------------
__global__ __launch_bounds__(256) void sniff_dtype(const unsigned short* __restrict__ u,
                                                   float* __restrict__ flag){
  __shared__ int cnt;
  if (threadIdx.x == 0) cnt = 0;
  __syncthreads();
  unsigned short b = u[2 * threadIdx.x];
  unsigned int w = ((unsigned int)b) << 16;
  float v = __uint_as_float(w);
  float a = fabsf(v);
  if (a >= 6.1e-5f && a <= 16384.f) atomicAdd(&cnt, 1);
  __syncthreads();
  if (threadIdx.x == 0) *flag = (cnt >= 128) ? 1.0f : 0.0f;
}

// ---------------- unified prep: casts + transposes + fills, flat 1-D grid ----------------
struct PrepBatch {
  const void* src[40];
  void*       dst[40];
  int         a[40];
  int         b[40];     // 0: cast, >0: wprep N, -1: fill 0, -2: fill 1
  int         blk0[41];
  int         ne;
};

__global__ __launch_bounds__(256) void prep_all(PrepBatch pb, const float* __restrict__ flag){
  int blk = blockIdx.x;
  int t = 0;
  while (t + 1 < pb.ne && pb.blk0[t + 1] <= blk) t++;
  int local = blk - pb.blk0[t];
  bool isbf = (*flag != 0.0f);
  const void* s = pb.src[t];
  int bt = pb.b[t];
  if (bt < 0){
    float val = (bt == -2) ? 1.0f : 0.0f;
    int n = pb.a[t];
    float* d = (float*)pb.dst[t];
    int v = local * 256 + threadIdx.x;
    int base = v * 4;
    if (base + 3 < n) ((float4*)d)[v] = make_float4(val, val, val, val);
    else for (int j = base; j < n && j < base + 4; j++) d[j] = val;
  } else if (bt == 0){
    int n = pb.a[t];
    float* d = (float*)pb.dst[t];
    int v = local * 256 + threadIdx.x;
    int base = v * 4;
    if (base + 3 < n){
      float4 f;
      if (isbf){
        ushort4 u = ((const ushort4*)s)[v];
        f.x = __uint_as_float(((unsigned)u.x) << 16);
        f.y = __uint_as_float(((unsigned)u.y) << 16);
        f.z = __uint_as_float(((unsigned)u.z) << 16);
        f.w = __uint_as_float(((unsigned)u.w) << 16);
      } else f = ((const float4*)s)[v];
      ((float4*)d)[v] = f;
    } else {
      for (int j = base; j < n && j < base + 4; j++) d[j] = loadf(s, j, isbf);
    }
  } else {
    int K = pb.a[t], Nn = bt, ldt = K + 8;
    short* d = (short*)pb.dst[t];
    int i = local * 256 + threadIdx.x;
    if (i < K * Nn){
      int n = i / K, k = i - n * K;
      d[(size_t)n * ldt + k] = f2bf(loadf(s, (size_t)k * Nn + n, isbf));
    }
  }
}

// ---------------- adjacency build ----------------
__global__ __launch_bounds__(256) void deg_edges(const int* __restrict__ dst, float* deg, int e){
  int i = blockIdx.x * 256 + threadIdx.x;
  if (i < e) atomicAdd(&deg[dst[i]], 1.0f);
}
__global__ __launch_bounds__(256) void adj_fin(const int* __restrict__ src, const int* __restrict__ dst,
                                               const float* __restrict__ deg,
                                               float* __restrict__ A, int n, int e){
  int i = blockIdx.x * 256 + threadIdx.x;
  if (i < n){
    float dv = rsqrtf(deg[i]);
    int g = i / MAXN, r = i - g * MAXN;
    atomicAdd(&A[(size_t)g * (MAXN * MAXN) + r * MAXN + r], dv * dv);
  } else if (i < n + e){
    int j = i - n;
    int s = src[j], d = dst[j];
    float nv = rsqrtf(deg[s]) * rsqrtf(deg[d]);
    int g = d / MAXN;
    int dl = d - g * MAXN;
    int sl = s - (s / MAXN) * MAXN;
    atomicAdd(&A[(size_t)g * (MAXN * MAXN) + dl * MAXN + sl], nv);
  }
}

// ---------------- gcn_all: whole GCN stage per graph, all-MFMA, 8 waves ----------------
#define GLDK 136
__global__ __launch_bounds__(512) void gcn_all(
    const void* __restrict__ X, const float* __restrict__ xflag,
    const float* __restrict__ Adj,
    const short* __restrict__ W1t, const float* __restrict__ b1,
    const short* __restrict__ W2t, const float* __restrict__ b2,
    short* __restrict__ xaggB,
    float* __restrict__ p1, float* __restrict__ p2)
{
  __shared__ short As[112 * GLDK];
  __shared__ short S1[112 * GLDK];
  __shared__ short S2[128 * GLDK];
  __shared__ short S4[128 * GLDK];
  int g = blockIdx.x;
  int tid = threadIdx.x;
  int wave = tid >> 6, lane = tid & 63;
  int quad = lane >> 4, l16 = lane & 15;
  int gn = wave * 16 + l16;
  bool isbf = (*xflag != 0.0f);

  for (int i = tid; i < 112 * GLDK / 2; i += 512){ ((int*)As)[i] = 0; ((int*)S1)[i] = 0; }
  for (int i = tid; i < 128 * GLDK / 2; i += 512){ ((int*)S2)[i] = 0; ((int*)S4)[i] = 0; }
  __syncthreads();

  const float* Ag = Adj + (size_t)g * (MAXN * MAXN);
  for (int i = tid; i < MAXN * MAXN; i += 512){
    int r = i / MAXN, s = i - r * MAXN;
    As[r * GLDK + s] = f2bf(Ag[i]);
  }
  for (int i = tid; i < MAXN * 16; i += 512){
    int r = i >> 4, k8 = (i & 15) << 3;
    s16x8 v;
    if (isbf){
      v = *reinterpret_cast<const s16x8*>((const short*)X + (size_t)(g * MAXN + r) * 128 + k8);
    } else {
      const float* ap = (const float*)X + (size_t)(g * MAXN + r) * 128 + k8;
      float4 f0 = *reinterpret_cast<const float4*>(ap);
      float4 f1 = *reinterpret_cast<const float4*>(ap + 4);
      v[0] = f2bf(f0.x); v[1] = f2bf(f0.y); v[2] = f2bf(f0.z); v[3] = f2bf(f0.w);
      v[4] = f2bf(f1.x); v[5] = f2bf(f1.y); v[6] = f2bf(f1.z); v[7] = f2bf(f1.w);
    }
    *reinterpret_cast<s16x8*>(&S1[r * GLDK + k8]) = v;
  }
  __syncthreads();

  f32x4 acc[7];
  auto zacc = [&](){
#pragma unroll
    for (int rt = 0; rt < 7; rt++) acc[rt] = (f32x4){0.f,0.f,0.f,0.f};
  };
  auto passL = [&](const short* Abuf, const short* Bbuf){
#pragma unroll
    for (int kt = 0; kt < 4; kt++){
      int kb = kt * 32 + quad * 8;
      s16x8 bf0 = *reinterpret_cast<const s16x8*>(&Bbuf[gn * GLDK + kb]);
#pragma unroll
      for (int rt = 0; rt < 7; rt++){
        s16x8 a = *reinterpret_cast<const s16x8*>(&Abuf[(rt * 16 + l16) * GLDK + kb]);
        acc[rt] = __builtin_amdgcn_mfma_f32_16x16x32_bf16(a, bf0, acc[rt], 0, 0, 0);
      }
    }
  };
  auto passG = [&](const short* Abuf, const short* __restrict__ Bt){
#pragma unroll
    for (int kt = 0; kt < 4; kt++){
      int kb = kt * 32 + quad * 8;
      s16x8 bf0 = *reinterpret_cast<const s16x8*>(&Bt[(size_t)gn * 136 + kb]);
#pragma unroll
      for (int rt = 0; rt < 7; rt++){
        s16x8 a = *reinterpret_cast<const s16x8*>(&Abuf[(rt * 16 + l16) * GLDK + kb]);
        acc[rt] = __builtin_amdgcn_mfma_f32_16x16x32_bf16(a, bf0, acc[rt], 0, 0, 0);
      }
    }
  };
  auto writeB = [&](short* Bbuf){
#pragma unroll
    for (int rt = 0; rt < 7; rt++){
      short4 o;
      o.x = f2bf(acc[rt][0]); o.y = f2bf(acc[rt][1]);
      o.z = f2bf(acc[rt][2]); o.w = f2bf(acc[rt][3]);
      *reinterpret_cast<short4*>(&Bbuf[gn * GLDK + rt * 16 + quad * 4]) = o;
    }
  };

  float s1sum = 0.f, s2sum = 0.f;
  auto hopEpi = [&](const float* bias, short* AoutA, short* BoutB, float& sum){
    float bv = bias[gn];
#pragma unroll
    for (int rt = 0; rt < 7; rt++){
      float vals[4];
#pragma unroll
      for (int r = 0; r < 4; r++){
        int row = rt * 16 + quad * 4 + r;
        float v = fmaxf(acc[rt][r] + bv, 0.f);
        vals[r] = v;
        if (row < MAXN) sum += v;
      }
      short4 o;
      o.x = f2bf(vals[0]); o.y = f2bf(vals[1]); o.z = f2bf(vals[2]); o.w = f2bf(vals[3]);
      *reinterpret_cast<short4*>(&BoutB[gn * GLDK + rt * 16 + quad * 4]) = o;
      if (AoutA){
        AoutA[(rt * 16 + quad * 4 + 0) * GLDK + gn] = o.x;
        AoutA[(rt * 16 + quad * 4 + 1) * GLDK + gn] = o.y;
        AoutA[(rt * 16 + quad * 4 + 2) * GLDK + gn] = o.z;
        AoutA[(rt * 16 + quad * 4 + 3) * GLDK + gn] = o.w;
      }
    }
  };
  auto xaggEpi = [&](int colbase){
    int col = gn + colbase;
#pragma unroll
    for (int rt = 0; rt < 7; rt++){
#pragma unroll
      for (int r = 0; r < 4; r++){
        int row = rt * 16 + quad * 4 + r;
        if (row < MAXN) xaggB[(size_t)(g * MAXN + row) * 256 + col] = f2bf(acc[rt][r]);
      }
    }
  };

  zacc(); passG(S1, W1t); writeB(S2);
  __syncthreads();
  zacc(); passL(As, S2); hopEpi(b1, S1, S4, s1sum);
  __syncthreads();
  zacc(); passL(As, S4); xaggEpi(0);
  zacc(); passG(S1, W2t); writeB(S2);
  __syncthreads();
  zacc(); passL(As, S2); hopEpi(b2, nullptr, S4, s2sum);
  __syncthreads();
  zacc(); passL(As, S4); xaggEpi(128);

  s1sum += __shfl_xor(s1sum, 16); s1sum += __shfl_xor(s1sum, 32);
  s2sum += __shfl_xor(s2sum, 16); s2sum += __shfl_xor(s2sum, 32);
  if (quad == 0){
    p1[g * 128 + gn] = s1sum;
    p2[g * 128 + gn] = s2sum;
  }
}

// ---------------- VdS GEMM: [Vd | S2d] = xagg @ WVSt^T + bias ----------------
// V half written TRANSPOSED bf16 to VTg[g][c][128-pad nodes]; scores to Sg[g][node][100].
__global__ __launch_bounds__(256) void gemm_vds(
    const short* __restrict__ A, int lda,
    const short* __restrict__ Bt, int ldbt,
    const float* __restrict__ bias,
    short* __restrict__ VTg, float* __restrict__ Sg,
    int M, int Nn)
{
  constexpr int K = 256, LDK = K + 8, KU = K / 8, KT = K / 32;
  __shared__ short As[64 * LDK];
  int bm = blockIdx.x * 64, bn = blockIdx.y * 128;
  int tid = threadIdx.x;
  int wave = tid >> 6, lane = tid & 63;
  int quad = lane >> 4, l16 = lane & 15;

  int gn0 = bn + wave * 16 + l16;
  int gn1 = gn0 + 64;
  s16x8 B0[KT], B1[KT];
#pragma unroll
  for (int kt = 0; kt < KT; kt++){
    int kb = kt * 32 + quad * 8;
    s16x8 z;
#pragma unroll
    for (int j = 0; j < 8; j++) z[j] = 0;
    B0[kt] = (gn0 < Nn) ? *reinterpret_cast<const s16x8*>(&Bt[(size_t)gn0 * ldbt + kb]) : z;
    B1[kt] = (gn1 < Nn) ? *reinterpret_cast<const s16x8*>(&Bt[(size_t)gn1 * ldbt + kb]) : z;
  }

  for (int u = tid; u < 64 * KU; u += 256){
    int r = u / KU, k8 = (u - r * KU) << 3;
    int gr = bm + r;
    s16x8 v;
    if (gr < M) v = *reinterpret_cast<const s16x8*>(A + (size_t)gr * lda + k8);
    else {
#pragma unroll
      for (int j = 0; j < 8; j++) v[j] = 0;
    }
    *reinterpret_cast<s16x8*>(&As[r * LDK + k8]) = v;
  }
  __syncthreads();

  f32x4 acc[4][2];
#pragma unroll
  for (int rt = 0; rt < 4; rt++)
#pragma unroll
    for (int g2 = 0; g2 < 2; g2++) acc[rt][g2] = (f32x4){0.f,0.f,0.f,0.f};

  const short* arow = &As[l16 * LDK];
#pragma unroll
  for (int kt = 0; kt < KT; kt++){
    int kb = kt * 32 + quad * 8;
#pragma unroll
    for (int rt = 0; rt < 4; rt++){
      s16x8 a = *reinterpret_cast<const s16x8*>(&arow[rt * 16 * LDK + kb]);
      acc[rt][0] = __builtin_amdgcn_mfma_f32_16x16x32_bf16(a, B0[kt], acc[rt][0], 0, 0, 0);
      acc[rt][1] = __builtin_amdgcn_mfma_f32_16x16x32_bf16(a, B1[kt], acc[rt][1], 0, 0, 0);
    }
  }

#pragma unroll
  for (int g2 = 0; g2 < 2; g2++){
    int gc = (g2 == 0) ? gn0 : gn1;
    if (gc >= Nn) continue;
    float bvv = bias[gc];
#pragma unroll
    for (int rt = 0; rt < 4; rt++){
      int gr0 = bm + rt * 16 + quad * 4;
      if (gc < 256){
        int ga = gr0 / MAXN, gb = (gr0 + 3) / MAXN;
        if (gr0 + 3 < M && ga == gb){
          int node = gr0 - ga * MAXN;
          short4 o;
          o.x = f2bf(acc[rt][g2][0] + bvv); o.y = f2bf(acc[rt][g2][1] + bvv);
          o.z = f2bf(acc[rt][g2][2] + bvv); o.w = f2bf(acc[rt][g2][3] + bvv);
          *reinterpret_cast<short4*>(&VTg[((size_t)ga * 256 + gc) * 128 + node]) = o;
        } else {
#pragma unroll
          for (int r = 0; r < 4; r++){
            int gr = gr0 + r;
            if (gr >= M) continue;
            int gg = gr / MAXN, node = gr - gg * MAXN;
            VTg[((size_t)gg * 256 + gc) * 128 + node] = f2bf(acc[rt][g2][r] + bvv);
          }
        }
      } else {
        int j = gc - 256;
#pragma unroll
        for (int r = 0; r < 4; r++){
          int gr = gr0 + r;
          if (gr >= M) continue;
          int gg = gr / MAXN, node = gr - gg * MAXN;
          Sg[(size_t)gg * 10000 + node * 100 + j] = acc[rt][g2][r] + bvv;
        }
      }
    }
  }
}

// ---------------- ubar_q0 ----------------
__global__ __launch_bounds__(256) void ubar_q0(const float* __restrict__ S0,
    const float* __restrict__ Wq0, const float* __restrict__ bq0,
    const float* __restrict__ Wk0, const float* __restrict__ bk0,
    float* __restrict__ Q0, short* __restrict__ Ubart, float* __restrict__ cvec)
{
  __shared__ float q0s[64];
  int j = blockIdx.x, h = j / 25, q = j - h * 25;
  int tid = threadIdx.x;
  if (tid < 64){
    int c = h * 64 + tid;
    float acc = bq0[c];
    for (int e = 0; e < 256; e++) acc = fmaf(S0[q * 256 + e], Wq0[e * 256 + c], acc);
    q0s[tid] = acc;
    Q0[q * 256 + c] = acc;
  }
  __syncthreads();
  float acc = 0.f;
  const float* wp = &Wk0[(size_t)tid * 256 + h * 64];
#pragma unroll
  for (int d = 0; d < 64; d++) acc = fmaf(wp[d], q0s[d], acc);
  Ubart[(size_t)j * 264 + tid] = f2bf(acc * 0.0625f);
  if (tid == 0){
    float cb = 0.f;
    for (int d = 0; d < 64; d++) cb = fmaf(bk0[h * 64 + d], q0s[d], cb);
    cvec[j] = cb * 0.0625f;
  }
}

// ---------------- tail_all: softmax + MFMA-AV + Wo0 + QKV + SAB + Wo1 + head ----------------
struct TailParams {
  const float* Sg;    const short* VTg;   const float* Q0;
  const short* Wo0t;  const float* bo0;
  const short* WQKVt; const float* biasQKV;
  const short* Wo1t;  const float* bo1;
  const float *S2, *Wq2, *bq2, *Wv2, *bv2, *Wo2, *bo2, *Wl, *bl, *Wc1, *bc1, *Wc2, *bc2, *Wc3, *bc3;
  float* out;
};

__global__ __launch_bounds__(512) void tail_all(TailParams P)
{
  __shared__ __align__(16) char pool[138240];
  float* Ssh  = (float*)(pool);            // [100][101]; later QKV [25][388]
  float* OaF  = (float*)(pool + 40400);    // [25][260]; later ObF [25][132]
  short* Abf  = (short*)(pool + 66400);    // [32][264]
  short* Abf2 = (short*)(pool + 83296);    // [32][136]
  float* Ss2  = (float*)(pool + 92000);    // [4][25][26]; later hpart
  short* Pbf  = (short*)(pool + 102400);   // [4][32][136]
  float* O1F  = (float*)(pool + 102400);   // [25][132] (after Pbf dead)
  float* hva  = (float*)(pool + 137216);
  float* hvb  = (float*)(pool + 137728);
  float* QKV = Ssh;
  float* ObF = OaF;
  float* hpart = Ss2;

  int g = blockIdx.x, tid = threadIdx.x;
  int wave = tid >> 6, lane = tid & 63, quad = lane >> 4, l16 = lane & 15;

  // stage scores (coalesced) + zero bf16 staging regions
  const float* sg = P.Sg + (size_t)g * 10000;
  for (int i = tid; i < 10000; i += 512){
    int k = i / 100, j = i - k * 100;
    Ssh[k * 101 + j] = sg[i];
  }
  for (int i = tid; i < 32 * 264 / 2; i += 512) ((int*)Abf)[i] = 0;
  for (int i = tid; i < 32 * 136 / 2; i += 512) ((int*)Abf2)[i] = 0;
  for (int i = tid; i < 34816 / 4; i += 512) ((int*)Pbf)[i] = 0;
  __syncthreads();

  // softmax over q per (k,h)
  for (int p = tid; p < 400; p += 512){
    int k = p >> 2, h = p & 3;
    float* base = &Ssh[k * 101 + h * 25];
    float m = -1e30f;
#pragma unroll
    for (int q = 0; q < 25; q++) m = fmaxf(m, base[q]);
    float s = 0.f;
#pragma unroll
    for (int q = 0; q < 25; q++){ float e = __expf(base[q] - m); base[q] = e; s += e; }
    float inv = 1.0f / s;
#pragma unroll
    for (int q = 0; q < 25; q++) base[q] *= inv;
  }
  __syncthreads();

  // P -> bf16 A-layout [h][q][k]
  for (int i = tid; i < 10000; i += 512){
    int h = i / 2500, rem = i - h * 2500;
    int q = rem / 100, k = rem - q * 100;
    Pbf[(h * 32 + q) * 136 + k] = f2bf(Ssh[k * 101 + h * 25 + q]);
  }
  __syncthreads();

  // AV via MFMA: wave w -> cols w*32..+31, h = w>>1; B-frags from global VT (L2)
  {
    int h = wave >> 1;
    int cbase = wave * 32;
    const short* vt = P.VTg + (size_t)g * 256 * 128;
    f32x4 acc[2][2];
#pragma unroll
    for (int rt = 0; rt < 2; rt++){ acc[rt][0] = (f32x4){0.f,0.f,0.f,0.f}; acc[rt][1] = acc[rt][0]; }
#pragma unroll
    for (int kt = 0; kt < 4; kt++){
      int kb = kt * 32 + quad * 8;
      s16x8 b0 = *reinterpret_cast<const s16x8*>(&vt[(size_t)(cbase + l16) * 128 + kb]);
      s16x8 b1 = *reinterpret_cast<const s16x8*>(&vt[(size_t)(cbase + 16 + l16) * 128 + kb]);
#pragma unroll
      for (int rt = 0; rt < 2; rt++){
        s16x8 a = *reinterpret_cast<const s16x8*>(&Pbf[(h * 32 + rt * 16 + l16) * 136 + kb]);
        acc[rt][0] = __builtin_amdgcn_mfma_f32_16x16x32_bf16(a, b0, acc[rt][0], 0, 0, 0);
        acc[rt][1] = __builtin_amdgcn_mfma_f32_16x16x32_bf16(a, b1, acc[rt][1], 0, 0, 0);
      }
    }
#pragma unroll
    for (int cg = 0; cg < 2; cg++){
      int c = cbase + cg * 16 + l16;
#pragma unroll
      for (int rt = 0; rt < 2; rt++){
#pragma unroll
        for (int r = 0; r < 4; r++){
          int row = rt * 16 + quad * 4 + r;
          if (row < 25){
            float oa = acc[rt][cg][r] + P.Q0[row * 256 + c];
            OaF[row * 260 + c] = oa;
            Abf[row * 264 + c] = f2bf(oa);
          }
        }
      }
    }
  }
  __syncthreads();

  // Wo0: O0 = Oa + relu(Oa @ Wo0 + bo0); per wave cols {c0, c0+128}
  {
    int c0 = wave * 16 + l16, c1 = c0 + 128;
    s16x8 B0[8], B1[8];
#pragma unroll
    for (int kt = 0; kt < 8; kt++){
      int kb = kt * 32 + quad * 8;
      B0[kt] = *reinterpret_cast<const s16x8*>(&P.Wo0t[(size_t)c0 * 264 + kb]);
      B1[kt] = *reinterpret_cast<const s16x8*>(&P.Wo0t[(size_t)c1 * 264 + kb]);
    }
    f32x4 a0[2], a1[2];
#pragma unroll
    for (int rt = 0; rt < 2; rt++){ a0[rt] = (f32x4){0.f,0.f,0.f,0.f}; a1[rt] = a0[rt]; }
#pragma unroll
    for (int kt = 0; kt < 8; kt++){
      int kb = kt * 32 + quad * 8;
#pragma unroll
      for (int rt = 0; rt < 2; rt++){
        s16x8 a = *reinterpret_cast<const s16x8*>(&Abf[(rt * 16 + l16) * 264 + kb]);
        a0[rt] = __builtin_amdgcn_mfma_f32_16x16x32_bf16(a, B0[kt], a0[rt], 0, 0, 0);
        a1[rt] = __builtin_amdgcn_mfma_f32_16x16x32_bf16(a, B1[kt], a1[rt], 0, 0, 0);
      }
    }
    __syncthreads();                    // all Oa reads done before O0 overwrites Abf
#pragma unroll
    for (int cg = 0; cg < 2; cg++){
      int col = cg ? c1 : c0;
      float bv = P.bo0[col];
#pragma unroll
      for (int rt = 0; rt < 2; rt++){
        f32x4 av = cg ? a1[rt] : a0[rt];
#pragma unroll
        for (int r = 0; r < 4; r++){
          int row = rt * 16 + quad * 4 + r;
          if (row < 25){
            float t = av[r] + bv;
            Abf[row * 264 + col] = f2bf(OaF[row * 260 + col] + fmaxf(t, 0.f));
          }
        }
      }
    }
  }
  __syncthreads();

  // QKV = O0 @ WQKVt + biasQKV (QKV aliases Ssh; scores dead)
  {
    int c0 = wave * 16 + l16;
    s16x8 B[3][8];
#pragma unroll
    for (int p2 = 0; p2 < 3; p2++)
#pragma unroll
      for (int kt = 0; kt < 8; kt++){
        int kb = kt * 32 + quad * 8;
        B[p2][kt] = *reinterpret_cast<const s16x8*>(&P.WQKVt[(size_t)(c0 + p2 * 128) * 264 + kb]);
      }
    f32x4 acc[3][2];
#pragma unroll
    for (int p2 = 0; p2 < 3; p2++)
#pragma unroll
      for (int rt = 0; rt < 2; rt++) acc[p2][rt] = (f32x4){0.f,0.f,0.f,0.f};
#pragma unroll
    for (int kt = 0; kt < 8; kt++){
      int kb = kt * 32 + quad * 8;
#pragma unroll
      for (int rt = 0; rt < 2; rt++){
        s16x8 a = *reinterpret_cast<const s16x8*>(&Abf[(rt * 16 + l16) * 264 + kb]);
#pragma unroll
        for (int p2 = 0; p2 < 3; p2++)
          acc[p2][rt] = __builtin_amdgcn_mfma_f32_16x16x32_bf16(a, B[p2][kt], acc[p2][rt], 0, 0, 0);
      }
    }
#pragma unroll
    for (int p2 = 0; p2 < 3; p2++){
      int col = c0 + p2 * 128;
      float bv = P.biasQKV[col];
#pragma unroll
      for (int rt = 0; rt < 2; rt++){
#pragma unroll
        for (int r = 0; r < 4; r++){
          int row = rt * 16 + quad * 4 + r;
          if (row < 25) QKV[row * 388 + col] = acc[p2][rt][r] + bv;
        }
      }
    }
  }
  __syncthreads();

  // SAB scores
  for (int idx = tid; idx < 2500; idx += 512){
    int h = idx / 625;
    int r = idx - h * 625;
    int q = r / 25, k = r - q * 25;
    const float* qp = &QKV[q * 388 + h * 32];
    const float* kp = &QKV[k * 388 + 128 + h * 32];
    float acc = 0.f;
#pragma unroll
    for (int d = 0; d < 32; d += 4){
      float4 a4 = *reinterpret_cast<const float4*>(&qp[d]);
      float4 b4 = *reinterpret_cast<const float4*>(&kp[d]);
      acc = fmaf(a4.x, b4.x, acc); acc = fmaf(a4.y, b4.y, acc);
      acc = fmaf(a4.z, b4.z, acc); acc = fmaf(a4.w, b4.w, acc);
    }
    Ss2[(h * 25 + q) * 26 + k] = acc * 0.0883883476f;
  }
  __syncthreads();
  if (tid < 100){
    int h = tid / 25, k = tid - h * 25;
    float m = -1e30f;
#pragma unroll
    for (int q = 0; q < 25; q++) m = fmaxf(m, Ss2[(h * 25 + q) * 26 + k]);
    float s = 0.f;
#pragma unroll
    for (int q = 0; q < 25; q++){ float e = __expf(Ss2[(h * 25 + q) * 26 + k] - m); Ss2[(h * 25 + q) * 26 + k] = e; s += e; }
    float inv = 1.0f / s;
#pragma unroll
    for (int q = 0; q < 25; q++) Ss2[(h * 25 + q) * 26 + k] *= inv;
  }
  __syncthreads();

  // Ob = Q1 + AV, q-split across tid<256 (nk=25, cheap)
  if (tid < 256){
    int qh = tid >> 7;
    int c = tid & 127, h = c >> 5;
    int q0 = qh * 13, nq = 13 - qh;
    float acc[13] = {};
    for (int k = 0; k < 25; k++){
      float v = QKV[k * 388 + 256 + c];
      for (int j = 0; j < nq; j++)
        acc[j] = fmaf(Ss2[(h * 25 + q0 + j) * 26 + k], v, acc[j]);
    }
    for (int j = 0; j < nq; j++){
      int q = q0 + j;
      float ob = QKV[q * 388 + c] + acc[j];
      ObF[q * 132 + c] = ob;
      Abf2[q * 136 + c] = f2bf(ob);
    }
  }
  __syncthreads();

  // O1 = Ob + relu(Ob @ Wo1 + bo1)  (O1F aliases Pbf region, Pbf dead)
  {
    int c0 = wave * 16 + l16;
    s16x8 B0[4];
#pragma unroll
    for (int kt = 0; kt < 4; kt++){
      int kb = kt * 32 + quad * 8;
      B0[kt] = *reinterpret_cast<const s16x8*>(&P.Wo1t[(size_t)c0 * 136 + kb]);
    }
    f32x4 a0 = (f32x4){0.f,0.f,0.f,0.f}, a1 = a0;
#pragma unroll
    for (int kt = 0; kt < 4; kt++){
      int kb = kt * 32 + quad * 8;
      s16x8 aA = *reinterpret_cast<const s16x8*>(&Abf2[l16 * 136 + kb]);
      s16x8 aB = *reinterpret_cast<const s16x8*>(&Abf2[(16 + l16) * 136 + kb]);
      a0 = __builtin_amdgcn_mfma_f32_16x16x32_bf16(aA, B0[kt], a0, 0, 0, 0);
      a1 = __builtin_amdgcn_mfma_f32_16x16x32_bf16(aB, B0[kt], a1, 0, 0, 0);
    }
    float bv = P.bo1[c0];
#pragma unroll
    for (int r = 0; r < 4; r++){
      int row0 = quad * 4 + r;
      if (row0 < 25){ float t = a0[r] + bv; O1F[row0 * 132 + c0] = ObF[row0 * 132 + c0] + fmaxf(t, 0.f); }
      int row1 = 16 + quad * 4 + r;
      if (row1 < 25){ float t = a1[r] + bv; O1F[row1 * 132 + c0] = ObF[row1 * 132 + c0] + fmaxf(t, 0.f); }
    }
  }
  __syncthreads();

  // head, split-k (hpart aliases Ss2, dead)
  if (tid < 128){
    float s = 0.f;
    for (int k = 0; k < 25; k++) s += O1F[k * 132 + tid];
    hva[tid] = s;
  }
  __syncthreads();
  {
    int kh = tid >> 7, c = tid & 127;
    if (tid < 256){
      float s = 0.f;
      for (int k = kh * 64; k < kh * 64 + 64; k++)
        s = fmaf(P.S2[k], P.Wq2[k * 128 + c], fmaf(hva[k], P.Wv2[k * 128 + c], s));
      hpart[kh * 128 + c] = s;
    }
    __syncthreads();
    if (tid < 128) hvb[c] = hpart[c] + hpart[128 + c] + P.bq2[c] + 25.f * P.bv2[c];
    __syncthreads();
    if (tid < 256){
      float s = 0.f;
      for (int k = kh * 64; k < kh * 64 + 64; k++) s = fmaf(hvb[k], P.Wo2[k * 128 + c], s);
      hpart[kh * 128 + c] = s;
    }
    __syncthreads();
    if (tid < 128) hva[c] = hvb[c] + fmaxf(hpart[c] + hpart[128 + c] + P.bo2[c], 0.f);
    __syncthreads();
    if (tid < 256){
      float s = 0.f;
      for (int k = kh * 64; k < kh * 64 + 64; k++) s = fmaf(hva[k], P.Wl[k * 128 + c], s);
      hpart[kh * 128 + c] = s;
    }
    __syncthreads();
    if (tid < 128) hvb[c] = hpart[c] + hpart[128 + c] + P.bl[c];
    __syncthreads();
    if (tid < 256){
      float s = 0.f;
      for (int k = kh * 64; k < kh * 64 + 64; k++) s = fmaf(hvb[k], P.Wc1[k * 128 + c], s);
      hpart[kh * 128 + c] = s;
    }
    __syncthreads();
    if (tid < 128) hva[c] = fmaxf(hpart[c] + hpart[128 + c] + P.bc1[c], 0.f);
    __syncthreads();
    if (tid < 128){
      int kh2 = tid >> 6, c2 = tid & 63;
      float s = 0.f;
      for (int k = kh2 * 64; k < kh2 * 64 + 64; k++) s = fmaf(hva[k], P.Wc2[k * 64 + c2], s);
      hpart[kh2 * 64 + c2] = s;
    }
    __syncthreads();
    if (tid < 64) hvb[tid] = fmaxf(hpart[tid] + hpart[64 + tid] + P.bc2[tid], 0.f);
    __syncthreads();
    if (tid < 10){
      float lg = P.bc3[tid];
      for (int k = 0; k < 64; k++) lg = fmaf(hvb[k], P.Wc3[k * 10 + tid], lg);
      P.out[g * 10 + tid] = lg;
    }
  }
}

// ---------------- host ----------------
extern "C" void kernel_launch(void* const* d_in, const int* in_sizes, int n_in,
                              void* d_out, int out_size, void* d_ws, size_t ws_size,
                              hipStream_t stream)
{
  const int*  edge = (const int*)d_in[1];
  const int N = in_sizes[0] / FIN;      // 20000
  const int E = in_sizes[1] / 2;        // 320000
  const int G = N / MAXN;               // 200
  const int* srcp = edge;
  const int* dstp = edge + E;
  float* out = (float*)d_out;           // f32: [logits 200x10 | p1 200x128 | p2 200x128]

  float* w = (float*)d_ws;
  size_t off = 0;
  auto alloc = [&](size_t nfl){ nfl = (nfl + 3) & ~(size_t)3; float* p = w + off; off += nfl; return p; };
  auto allocS = [&](size_t nsh)->short*{ size_t nfl = ((nsh + 1) / 2 + 3) & ~(size_t)3; short* p = (short*)(w + off); off += nfl; return p; };

  float* dflag = alloc(1);
  float* degb  = alloc(N);

  float* biasVS  = alloc(356);          // [bv0 | cvec]
  float* biasQKV = alloc(384);          // [bq1 | bk1 | bv1]
  float* cvec = biasVS + 256;

  const int castT[24] = {4,6,7,8,9,10,11,15,23,24,25,26,29,30,31,32,33,34,35,36,37,38,39,40};
  float* wf[41] = {nullptr};
  for (int i = 0; i < 24; i++) wf[castT[i]] = alloc((size_t)in_sizes[castT[i]]);
  wf[13] = biasVS; wf[17] = biasQKV; wf[19] = biasQKV + 128; wf[21] = biasQKV + 256;

  float* Sg  = alloc((size_t)G * 10000);           // scores [g][node][100]
  short* VTg = allocS((size_t)G * 256 * 128);      // V^T bf16, node-padded to 128
  float* Adj = alloc((size_t)G * MAXN * MAXN);
  float* Q0  = alloc(25 * 256);
  short* xaggB = allocS((size_t)N * 256);

  short* W1t   = allocS(128 * 136);
  short* W2t   = allocS(128 * 136);
  short* WVSt  = allocS(356 * 264);     // [Wv0t | Ubart]
  short* WQKVt = allocS(384 * 264);     // [Wq1t | Wk1t | Wv1t]
  short* Wo0t  = allocS(256 * 264);
  short* Wo1t  = allocS(128 * 136);
  short* Ubart = WVSt + (size_t)256 * 264;
  if (off * sizeof(float) > ws_size) return;

  dim3 blk(256);

  // 1. dtype sniff
  sniff_dtype<<<1, blk, 0, stream>>>((const unsigned short*)d_in[0], dflag);

  // 2. unified prep (casts + transposes + fills: Adj=0, deg=1, VTg=0)
  PrepBatch pb; int ne = 0, blks = 0;
  auto addC = [&](const void* s, float* d, int n){
    pb.src[ne]=s; pb.dst[ne]=d; pb.a[ne]=n; pb.b[ne]=0; pb.blk0[ne]=blks;
    blks += ceil_div(ceil_div(n, 4), 256); ne++; };
  auto addW = [&](const void* s, short* d, int K, int Nn){
    pb.src[ne]=s; pb.dst[ne]=d; pb.a[ne]=K; pb.b[ne]=Nn; pb.blk0[ne]=blks;
    blks += ceil_div(K * Nn, 256); ne++; };
  auto addF = [&](void* d, int n, int mode){
    pb.src[ne]=nullptr; pb.dst[ne]=d; pb.a[ne]=n; pb.b[ne]=mode; pb.blk0[ne]=blks;
    blks += ceil_div(ceil_div(n, 4), 256); ne++; };
  for (int i = 0; i < 24; i++){ int t = castT[i]; addC(d_in[t], wf[t], in_sizes[t]); }
  addC(d_in[13], biasVS, 256);
  addC(d_in[17], biasQKV, 128); addC(d_in[19], biasQKV + 128, 128); addC(d_in[21], biasQKV + 256, 128);
  addW(d_in[3],  W1t, 128, 128);             addW(d_in[5],  W2t, 128, 128);
  addW(d_in[12], WVSt, 256, 256);            addW(d_in[16], WQKVt, 256, 128);
  addW(d_in[18], WQKVt + 128*264, 256, 128); addW(d_in[20], WQKVt + 256*264, 256, 128);
  addW(d_in[14], Wo0t, 256, 256);            addW(d_in[22], Wo1t, 128, 128);
  addF(Adj, G * MAXN * MAXN, -1);
  addF(degb, N, -2);
  addF(VTg, G * 256 * 128 / 2, -1);          // zero bf16 V^T (incl. node pads)
  pb.blk0[ne] = blks; pb.ne = ne;
  prep_all<<<dim3(blks), blk, 0, stream>>>(pb, dflag);

  // 3-4. adjacency
  deg_edges<<<ceil_div(E, 256), blk, 0, stream>>>(dstp, degb, E);
  adj_fin<<<ceil_div(N + E, 256), blk, 0, stream>>>(srcp, dstp, degb, Adj, N, E);

  // 5. whole GCN stage per graph (8 waves/block)
  gcn_all<<<dim3(G), dim3(512), 0, stream>>>(d_in[0], dflag, Adj, W1t, wf[4], W2t, wf[6],
                                             xaggB, out + 2000, out + 27600);

  // 6. Q0 + Ubar^T + cvec
  ubar_q0<<<dim3(100), blk, 0, stream>>>(wf[7], wf[8], wf[9], wf[10], wf[11], Q0, Ubart, cvec);

  // 7. VdS GEMM: V half transposed bf16 -> VTg; scores -> Sg
  {
    dim3 grid(ceil_div(N, 64), 3);
    gemm_vds<<<grid, blk, 0, stream>>>(xaggB, 256, WVSt, 264, biasVS, VTg, Sg, N, 356);
  }

  // 8. fused tail (8 waves/block, MFMA AV)
  TailParams tp;
  tp.Sg = Sg; tp.VTg = VTg; tp.Q0 = Q0;
  tp.Wo0t = Wo0t; tp.bo0 = wf[15];
  tp.WQKVt = WQKVt; tp.biasQKV = biasQKV;
  tp.Wo1t = Wo1t; tp.bo1 = wf[23];
  tp.S2 = wf[24]; tp.Wq2 = wf[25]; tp.bq2 = wf[26]; tp.Wv2 = wf[29]; tp.bv2 = wf[30];
  tp.Wo2 = wf[31]; tp.bo2 = wf[32]; tp.Wl = wf[33]; tp.bl = wf[34];
  tp.Wc1 = wf[35]; tp.bc1 = wf[36]; tp.Wc2 = wf[37]; tp.bc2 = wf[38];
  tp.Wc3 = wf[39]; tp.bc3 = wf[40];
  tp.out = out;
  tail_all<<<dim3(G), dim3(512), 0, stream>>>(tp);
}

// Round 15
// 263.271 us; speedup vs baseline: 1.1223x; 1.1223x over previous
//
#include <hip/hip_runtime.h>
#include <hip/hip_bf16.h>
#include <cstdint>
#include <cstddef>

typedef __hip_bfloat16 bf16;
typedef __attribute__((ext_vector_type(8))) short s16x8;
typedef __attribute__((ext_vector_type(4))) float f32x4;

#define MAXN 100
#define HH   4
#define FIN  128
#define KS1  25

static inline int ceil_div(int a, int b){ return (a + b - 1) / b; }

__device__ inline short f2bf(float f){               // RNE float->bf16 bits
  unsigned int u = __float_as_uint(f);
  u = (u + 0x7FFF + ((u >> 16) & 1)) >> 16;
  return (short)u;
}
__device__ inline float loadf(const void* s, int i, bool isbf){
  return isbf ? __bfloat162float(((const bf16*)s)[i]) : ((const float*)s)[i];
}
// per-block dtype sniff: wave-0 lanes sample x's even half-words; bf16 data decodes
// sane ~100%, f32 low-halves ~11% -> popcount threshold 32 of 64.
__device__ inline bool block_sniff(const void* x, int tid, int* flagS){
  if (tid < 64){
    unsigned short b = ((const unsigned short*)x)[2 * tid];
    float v = __uint_as_float(((unsigned)b) << 16);
    float a = fabsf(v);
    bool ok = (a >= 6.1e-5f && a <= 16384.f);
    unsigned long long m = __ballot(ok);
    if (tid == 0) *flagS = (__popcll(m) >= 32) ? 1 : 0;
  }
  __syncthreads();
  return *flagS != 0;
}

// ---------------- unified prep: casts + transposes + fills, flat 1-D grid ----------------
struct PrepBatch {
  const void* src[40];
  void*       dst[40];
  int         a[40];
  int         b[40];     // 0: cast, >0: wprep N, -1: fill 0, -2: fill 1
  int         blk0[41];
  int         ne;
  const void* xptr;      // for inline sniff
};

__global__ __launch_bounds__(256) void prep_all(PrepBatch pb){
  __shared__ int flagS;
  int tid = threadIdx.x;
  bool isbf = block_sniff(pb.xptr, tid, &flagS);
  int blk = blockIdx.x;
  int t = 0;
  while (t + 1 < pb.ne && pb.blk0[t + 1] <= blk) t++;
  int local = blk - pb.blk0[t];
  const void* s = pb.src[t];
  int bt = pb.b[t];
  if (bt < 0){
    float val = (bt == -2) ? 1.0f : 0.0f;
    int n = pb.a[t];
    float* d = (float*)pb.dst[t];
    int v = local * 256 + tid;
    int base = v * 4;
    if (base + 3 < n) ((float4*)d)[v] = make_float4(val, val, val, val);
    else for (int j = base; j < n && j < base + 4; j++) d[j] = val;
  } else if (bt == 0){
    int n = pb.a[t];
    float* d = (float*)pb.dst[t];
    int v = local * 256 + tid;
    int base = v * 4;
    if (base + 3 < n){
      float4 f;
      if (isbf){
        ushort4 u = ((const ushort4*)s)[v];
        f.x = __uint_as_float(((unsigned)u.x) << 16);
        f.y = __uint_as_float(((unsigned)u.y) << 16);
        f.z = __uint_as_float(((unsigned)u.z) << 16);
        f.w = __uint_as_float(((unsigned)u.w) << 16);
      } else f = ((const float4*)s)[v];
      ((float4*)d)[v] = f;
    } else {
      for (int j = base; j < n && j < base + 4; j++) d[j] = loadf(s, j, isbf);
    }
  } else {
    int K = pb.a[t], Nn = bt, ldt = K + 8;
    short* d = (short*)pb.dst[t];
    int i = local * 256 + tid;
    if (i < K * Nn){
      int n = i / K, k = i - n * K;
      d[(size_t)n * ldt + k] = f2bf(loadf(s, (size_t)k * Nn + n, isbf));
    }
  }
}

// ---------------- adjacency count: cnt[g][dl][sl] += 1 per edge (exact in fp32) ----------------
__global__ __launch_bounds__(256) void adj_cnt(const int* __restrict__ src, const int* __restrict__ dst,
                                               float* __restrict__ A, int e){
  int i = blockIdx.x * 256 + threadIdx.x;
  if (i >= e) return;
  int s = src[i], d = dst[i];
  int g = d / MAXN;
  int dl = d - g * MAXN;
  int sl = s - (s / MAXN) * MAXN;
  atomicAdd(&A[(size_t)g * (MAXN * MAXN) + dl * MAXN + sl], 1.0f);
}

// ---------------- gcn_all: deg+normalize in-block, whole GCN stage, all-MFMA, 8 waves ----------------
#define GLDK 136
__global__ __launch_bounds__(512) void gcn_all(
    const void* __restrict__ X,
    const float* __restrict__ Adj,           // unnormalized counts
    const short* __restrict__ W1t, const float* __restrict__ b1,
    const short* __restrict__ W2t, const float* __restrict__ b2,
    short* __restrict__ xaggB,
    float* __restrict__ p1, float* __restrict__ p2)
{
  __shared__ short As[112 * GLDK];
  __shared__ short S1[112 * GLDK];
  __shared__ short S2[128 * GLDK];
  __shared__ short S4[128 * GLDK];
  __shared__ float dinvL[112];
  __shared__ int flagS;
  int g = blockIdx.x;
  int tid = threadIdx.x;
  bool isbf = block_sniff(X, tid, &flagS);
  int wave = tid >> 6, lane = tid & 63;
  int quad = lane >> 4, l16 = lane & 15;
  int gn = wave * 16 + l16;

  for (int i = tid; i < 112 * GLDK / 2; i += 512){ ((int*)As)[i] = 0; ((int*)S1)[i] = 0; }
  for (int i = tid; i < 128 * GLDK / 2; i += 512){ ((int*)S2)[i] = 0; ((int*)S4)[i] = 0; }

  const float* Ag = Adj + (size_t)g * (MAXN * MAXN);
  // deg[r] = 1 (self-loop) + rowsum(cnt); dinv = rsqrt
  if (tid < MAXN){
    float s = 0.f;
    const float* row = Ag + tid * MAXN;
    for (int j = 0; j < MAXN; j++) s += row[j];
    dinvL[tid] = rsqrtf(1.0f + s);
  }
  __syncthreads();

  // stage normalized adjacency: (cnt + delta) * dinv[r]*dinv[s]
  for (int i = tid; i < MAXN * MAXN; i += 512){
    int r = i / MAXN, s = i - r * MAXN;
    float v = Ag[i] + (r == s ? 1.0f : 0.0f);
    As[r * GLDK + s] = f2bf(v * dinvL[r] * dinvL[s]);
  }
  for (int i = tid; i < MAXN * 16; i += 512){
    int r = i >> 4, k8 = (i & 15) << 3;
    s16x8 v;
    if (isbf){
      v = *reinterpret_cast<const s16x8*>((const short*)X + (size_t)(g * MAXN + r) * 128 + k8);
    } else {
      const float* ap = (const float*)X + (size_t)(g * MAXN + r) * 128 + k8;
      float4 f0 = *reinterpret_cast<const float4*>(ap);
      float4 f1 = *reinterpret_cast<const float4*>(ap + 4);
      v[0] = f2bf(f0.x); v[1] = f2bf(f0.y); v[2] = f2bf(f0.z); v[3] = f2bf(f0.w);
      v[4] = f2bf(f1.x); v[5] = f2bf(f1.y); v[6] = f2bf(f1.z); v[7] = f2bf(f1.w);
    }
    *reinterpret_cast<s16x8*>(&S1[r * GLDK + k8]) = v;
  }
  __syncthreads();

  f32x4 acc[7];
  auto zacc = [&](){
#pragma unroll
    for (int rt = 0; rt < 7; rt++) acc[rt] = (f32x4){0.f,0.f,0.f,0.f};
  };
  auto passL = [&](const short* Abuf, const short* Bbuf){
#pragma unroll
    for (int kt = 0; kt < 4; kt++){
      int kb = kt * 32 + quad * 8;
      s16x8 bf0 = *reinterpret_cast<const s16x8*>(&Bbuf[gn * GLDK + kb]);
#pragma unroll
      for (int rt = 0; rt < 7; rt++){
        s16x8 a = *reinterpret_cast<const s16x8*>(&Abuf[(rt * 16 + l16) * GLDK + kb]);
        acc[rt] = __builtin_amdgcn_mfma_f32_16x16x32_bf16(a, bf0, acc[rt], 0, 0, 0);
      }
    }
  };
  auto passG = [&](const short* Abuf, const short* __restrict__ Bt){
#pragma unroll
    for (int kt = 0; kt < 4; kt++){
      int kb = kt * 32 + quad * 8;
      s16x8 bf0 = *reinterpret_cast<const s16x8*>(&Bt[(size_t)gn * 136 + kb]);
#pragma unroll
      for (int rt = 0; rt < 7; rt++){
        s16x8 a = *reinterpret_cast<const s16x8*>(&Abuf[(rt * 16 + l16) * GLDK + kb]);
        acc[rt] = __builtin_amdgcn_mfma_f32_16x16x32_bf16(a, bf0, acc[rt], 0, 0, 0);
      }
    }
  };
  auto writeB = [&](short* Bbuf){
#pragma unroll
    for (int rt = 0; rt < 7; rt++){
      short4 o;
      o.x = f2bf(acc[rt][0]); o.y = f2bf(acc[rt][1]);
      o.z = f2bf(acc[rt][2]); o.w = f2bf(acc[rt][3]);
      *reinterpret_cast<short4*>(&Bbuf[gn * GLDK + rt * 16 + quad * 4]) = o;
    }
  };

  float s1sum = 0.f, s2sum = 0.f;
  auto hopEpi = [&](const float* bias, short* AoutA, short* BoutB, float& sum){
    float bv = bias[gn];
#pragma unroll
    for (int rt = 0; rt < 7; rt++){
      float vals[4];
#pragma unroll
      for (int r = 0; r < 4; r++){
        int row = rt * 16 + quad * 4 + r;
        float v = fmaxf(acc[rt][r] + bv, 0.f);
        vals[r] = v;
        if (row < MAXN) sum += v;
      }
      short4 o;
      o.x = f2bf(vals[0]); o.y = f2bf(vals[1]); o.z = f2bf(vals[2]); o.w = f2bf(vals[3]);
      *reinterpret_cast<short4*>(&BoutB[gn * GLDK + rt * 16 + quad * 4]) = o;
      if (AoutA){
        AoutA[(rt * 16 + quad * 4 + 0) * GLDK + gn] = o.x;
        AoutA[(rt * 16 + quad * 4 + 1) * GLDK + gn] = o.y;
        AoutA[(rt * 16 + quad * 4 + 2) * GLDK + gn] = o.z;
        AoutA[(rt * 16 + quad * 4 + 3) * GLDK + gn] = o.w;
      }
    }
  };
  auto xaggEpi = [&](int colbase){
    int col = gn + colbase;
#pragma unroll
    for (int rt = 0; rt < 7; rt++){
#pragma unroll
      for (int r = 0; r < 4; r++){
        int row = rt * 16 + quad * 4 + r;
        if (row < MAXN) xaggB[(size_t)(g * MAXN + row) * 256 + col] = f2bf(acc[rt][r]);
      }
    }
  };

  zacc(); passG(S1, W1t); writeB(S2);
  __syncthreads();
  zacc(); passL(As, S2); hopEpi(b1, S1, S4, s1sum);
  __syncthreads();
  zacc(); passL(As, S4); xaggEpi(0);
  zacc(); passG(S1, W2t); writeB(S2);
  __syncthreads();
  zacc(); passL(As, S2); hopEpi(b2, nullptr, S4, s2sum);
  __syncthreads();
  zacc(); passL(As, S4); xaggEpi(128);

  s1sum += __shfl_xor(s1sum, 16); s1sum += __shfl_xor(s1sum, 32);
  s2sum += __shfl_xor(s2sum, 16); s2sum += __shfl_xor(s2sum, 32);
  if (quad == 0){
    p1[g * 128 + gn] = s1sum;
    p2[g * 128 + gn] = s2sum;
  }
}

// ---------------- VdS GEMM: [Vd | S2d] = xagg @ WVSt^T + bias ----------------
__global__ __launch_bounds__(256) void gemm_vds(
    const short* __restrict__ A, int lda,
    const short* __restrict__ Bt, int ldbt,
    const float* __restrict__ bias,
    short* __restrict__ VTg, float* __restrict__ Sg,
    int M, int Nn)
{
  constexpr int K = 256, LDK = K + 8, KU = K / 8, KT = K / 32;
  __shared__ short As[64 * LDK];
  int bm = blockIdx.x * 64, bn = blockIdx.y * 128;
  int tid = threadIdx.x;
  int wave = tid >> 6, lane = tid & 63;
  int quad = lane >> 4, l16 = lane & 15;

  int gn0 = bn + wave * 16 + l16;
  int gn1 = gn0 + 64;
  s16x8 B0[KT], B1[KT];
#pragma unroll
  for (int kt = 0; kt < KT; kt++){
    int kb = kt * 32 + quad * 8;
    s16x8 z;
#pragma unroll
    for (int j = 0; j < 8; j++) z[j] = 0;
    B0[kt] = (gn0 < Nn) ? *reinterpret_cast<const s16x8*>(&Bt[(size_t)gn0 * ldbt + kb]) : z;
    B1[kt] = (gn1 < Nn) ? *reinterpret_cast<const s16x8*>(&Bt[(size_t)gn1 * ldbt + kb]) : z;
  }

  for (int u = tid; u < 64 * KU; u += 256){
    int r = u / KU, k8 = (u - r * KU) << 3;
    int gr = bm + r;
    s16x8 v;
    if (gr < M) v = *reinterpret_cast<const s16x8*>(A + (size_t)gr * lda + k8);
    else {
#pragma unroll
      for (int j = 0; j < 8; j++) v[j] = 0;
    }
    *reinterpret_cast<s16x8*>(&As[r * LDK + k8]) = v;
  }
  __syncthreads();

  f32x4 acc[4][2];
#pragma unroll
  for (int rt = 0; rt < 4; rt++)
#pragma unroll
    for (int g2 = 0; g2 < 2; g2++) acc[rt][g2] = (f32x4){0.f,0.f,0.f,0.f};

  const short* arow = &As[l16 * LDK];
#pragma unroll
  for (int kt = 0; kt < KT; kt++){
    int kb = kt * 32 + quad * 8;
#pragma unroll
    for (int rt = 0; rt < 4; rt++){
      s16x8 a = *reinterpret_cast<const s16x8*>(&arow[rt * 16 * LDK + kb]);
      acc[rt][0] = __builtin_amdgcn_mfma_f32_16x16x32_bf16(a, B0[kt], acc[rt][0], 0, 0, 0);
      acc[rt][1] = __builtin_amdgcn_mfma_f32_16x16x32_bf16(a, B1[kt], acc[rt][1], 0, 0, 0);
    }
  }

#pragma unroll
  for (int g2 = 0; g2 < 2; g2++){
    int gc = (g2 == 0) ? gn0 : gn1;
    if (gc >= Nn) continue;
    float bvv = bias[gc];
#pragma unroll
    for (int rt = 0; rt < 4; rt++){
      int gr0 = bm + rt * 16 + quad * 4;
      if (gc < 256){
        int ga = gr0 / MAXN, gb = (gr0 + 3) / MAXN;
        if (gr0 + 3 < M && ga == gb){
          int node = gr0 - ga * MAXN;
          short4 o;
          o.x = f2bf(acc[rt][g2][0] + bvv); o.y = f2bf(acc[rt][g2][1] + bvv);
          o.z = f2bf(acc[rt][g2][2] + bvv); o.w = f2bf(acc[rt][g2][3] + bvv);
          *reinterpret_cast<short4*>(&VTg[((size_t)ga * 256 + gc) * 128 + node]) = o;
        } else {
#pragma unroll
          for (int r = 0; r < 4; r++){
            int gr = gr0 + r;
            if (gr >= M) continue;
            int gg = gr / MAXN, node = gr - gg * MAXN;
            VTg[((size_t)gg * 256 + gc) * 128 + node] = f2bf(acc[rt][g2][r] + bvv);
          }
        }
      } else {
        int j = gc - 256;
#pragma unroll
        for (int r = 0; r < 4; r++){
          int gr = gr0 + r;
          if (gr >= M) continue;
          int gg = gr / MAXN, node = gr - gg * MAXN;
          Sg[(size_t)gg * 10000 + node * 100 + j] = acc[rt][g2][r] + bvv;
        }
      }
    }
  }
}

// ---------------- ubar_q0 ----------------
__global__ __launch_bounds__(256) void ubar_q0(const float* __restrict__ S0,
    const float* __restrict__ Wq0, const float* __restrict__ bq0,
    const float* __restrict__ Wk0, const float* __restrict__ bk0,
    float* __restrict__ Q0, short* __restrict__ Ubart, float* __restrict__ cvec)
{
  __shared__ float q0s[64];
  int j = blockIdx.x, h = j / 25, q = j - h * 25;
  int tid = threadIdx.x;
  if (tid < 64){
    int c = h * 64 + tid;
    float acc = bq0[c];
    for (int e = 0; e < 256; e++) acc = fmaf(S0[q * 256 + e], Wq0[e * 256 + c], acc);
    q0s[tid] = acc;
    Q0[q * 256 + c] = acc;
  }
  __syncthreads();
  float acc = 0.f;
  const float* wp = &Wk0[(size_t)tid * 256 + h * 64];
#pragma unroll
  for (int d = 0; d < 64; d++) acc = fmaf(wp[d], q0s[d], acc);
  Ubart[(size_t)j * 264 + tid] = f2bf(acc * 0.0625f);
  if (tid == 0){
    float cb = 0.f;
    for (int d = 0; d < 64; d++) cb = fmaf(bk0[h * 64 + d], q0s[d], cb);
    cvec[j] = cb * 0.0625f;
  }
}

// ---------------- tail_all: softmax + MFMA-AV + Wo0 + QKV + SAB + Wo1 + head ----------------
struct TailParams {
  const float* Sg;    const short* VTg;   const float* Q0;
  const short* Wo0t;  const float* bo0;
  const short* WQKVt; const float* biasQKV;
  const short* Wo1t;  const float* bo1;
  const float *S2, *Wq2, *bq2, *Wv2, *bv2, *Wo2, *bo2, *Wl, *bl, *Wc1, *bc1, *Wc2, *bc2, *Wc3, *bc3;
  float* out;
};

__global__ __launch_bounds__(512) void tail_all(TailParams P)
{
  __shared__ __align__(16) char pool[138240];
  float* Ssh  = (float*)(pool);            // [100][101]; later QKV [25][388]
  float* OaF  = (float*)(pool + 40400);    // [25][260]; later ObF [25][132]
  short* Abf  = (short*)(pool + 66400);    // [32][264]
  short* Abf2 = (short*)(pool + 83296);    // [32][136]
  float* Ss2  = (float*)(pool + 92000);    // [4][25][26]; later hpart
  short* Pbf  = (short*)(pool + 102400);   // [4][32][136]
  float* O1F  = (float*)(pool + 102400);   // [25][132] (after Pbf dead)
  float* hva  = (float*)(pool + 137216);
  float* hvb  = (float*)(pool + 137728);
  float* QKV = Ssh;
  float* ObF = OaF;
  float* hpart = Ss2;

  int g = blockIdx.x, tid = threadIdx.x;
  int wave = tid >> 6, lane = tid & 63, quad = lane >> 4, l16 = lane & 15;

  const float* sg = P.Sg + (size_t)g * 10000;
  for (int i = tid; i < 10000; i += 512){
    int k = i / 100, j = i - k * 100;
    Ssh[k * 101 + j] = sg[i];
  }
  for (int i = tid; i < 32 * 264 / 2; i += 512) ((int*)Abf)[i] = 0;
  for (int i = tid; i < 32 * 136 / 2; i += 512) ((int*)Abf2)[i] = 0;
  for (int i = tid; i < 34816 / 4; i += 512) ((int*)Pbf)[i] = 0;
  __syncthreads();

  for (int p = tid; p < 400; p += 512){
    int k = p >> 2, h = p & 3;
    float* base = &Ssh[k * 101 + h * 25];
    float m = -1e30f;
#pragma unroll
    for (int q = 0; q < 25; q++) m = fmaxf(m, base[q]);
    float s = 0.f;
#pragma unroll
    for (int q = 0; q < 25; q++){ float e = __expf(base[q] - m); base[q] = e; s += e; }
    float inv = 1.0f / s;
#pragma unroll
    for (int q = 0; q < 25; q++) base[q] *= inv;
  }
  __syncthreads();

  for (int i = tid; i < 10000; i += 512){
    int h = i / 2500, rem = i - h * 2500;
    int q = rem / 100, k = rem - q * 100;
    Pbf[(h * 32 + q) * 136 + k] = f2bf(Ssh[k * 101 + h * 25 + q]);
  }
  __syncthreads();

  // AV via MFMA: wave w -> cols w*32..+31, h = w>>1; B-frags from global VT (L2)
  {
    int h = wave >> 1;
    int cbase = wave * 32;
    const short* vt = P.VTg + (size_t)g * 256 * 128;
    f32x4 acc[2][2];
#pragma unroll
    for (int rt = 0; rt < 2; rt++){ acc[rt][0] = (f32x4){0.f,0.f,0.f,0.f}; acc[rt][1] = acc[rt][0]; }
#pragma unroll
    for (int kt = 0; kt < 4; kt++){
      int kb = kt * 32 + quad * 8;
      s16x8 b0 = *reinterpret_cast<const s16x8*>(&vt[(size_t)(cbase + l16) * 128 + kb]);
      s16x8 b1 = *reinterpret_cast<const s16x8*>(&vt[(size_t)(cbase + 16 + l16) * 128 + kb]);
#pragma unroll
      for (int rt = 0; rt < 2; rt++){
        s16x8 a = *reinterpret_cast<const s16x8*>(&Pbf[(h * 32 + rt * 16 + l16) * 136 + kb]);
        acc[rt][0] = __builtin_amdgcn_mfma_f32_16x16x32_bf16(a, b0, acc[rt][0], 0, 0, 0);
        acc[rt][1] = __builtin_amdgcn_mfma_f32_16x16x32_bf16(a, b1, acc[rt][1], 0, 0, 0);
      }
    }
#pragma unroll
    for (int cg = 0; cg < 2; cg++){
      int c = cbase + cg * 16 + l16;
#pragma unroll
      for (int rt = 0; rt < 2; rt++){
#pragma unroll
        for (int r = 0; r < 4; r++){
          int row = rt * 16 + quad * 4 + r;
          if (row < 25){
            float oa = acc[rt][cg][r] + P.Q0[row * 256 + c];
            OaF[row * 260 + c] = oa;
            Abf[row * 264 + c] = f2bf(oa);
          }
        }
      }
    }
  }
  __syncthreads();

  // Wo0
  {
    int c0 = wave * 16 + l16, c1 = c0 + 128;
    s16x8 B0[8], B1[8];
#pragma unroll
    for (int kt = 0; kt < 8; kt++){
      int kb = kt * 32 + quad * 8;
      B0[kt] = *reinterpret_cast<const s16x8*>(&P.Wo0t[(size_t)c0 * 264 + kb]);
      B1[kt] = *reinterpret_cast<const s16x8*>(&P.Wo0t[(size_t)c1 * 264 + kb]);
    }
    f32x4 a0[2], a1[2];
#pragma unroll
    for (int rt = 0; rt < 2; rt++){ a0[rt] = (f32x4){0.f,0.f,0.f,0.f}; a1[rt] = a0[rt]; }
#pragma unroll
    for (int kt = 0; kt < 8; kt++){
      int kb = kt * 32 + quad * 8;
#pragma unroll
      for (int rt = 0; rt < 2; rt++){
        s16x8 a = *reinterpret_cast<const s16x8*>(&Abf[(rt * 16 + l16) * 264 + kb]);
        a0[rt] = __builtin_amdgcn_mfma_f32_16x16x32_bf16(a, B0[kt], a0[rt], 0, 0, 0);
        a1[rt] = __builtin_amdgcn_mfma_f32_16x16x32_bf16(a, B1[kt], a1[rt], 0, 0, 0);
      }
    }
    __syncthreads();
#pragma unroll
    for (int cg = 0; cg < 2; cg++){
      int col = cg ? c1 : c0;
      float bv = P.bo0[col];
#pragma unroll
      for (int rt = 0; rt < 2; rt++){
        f32x4 av = cg ? a1[rt] : a0[rt];
#pragma unroll
        for (int r = 0; r < 4; r++){
          int row = rt * 16 + quad * 4 + r;
          if (row < 25){
            float t = av[r] + bv;
            Abf[row * 264 + col] = f2bf(OaF[row * 260 + col] + fmaxf(t, 0.f));
          }
        }
      }
    }
  }
  __syncthreads();

  // QKV
  {
    int c0 = wave * 16 + l16;
    s16x8 B[3][8];
#pragma unroll
    for (int p2 = 0; p2 < 3; p2++)
#pragma unroll
      for (int kt = 0; kt < 8; kt++){
        int kb = kt * 32 + quad * 8;
        B[p2][kt] = *reinterpret_cast<const s16x8*>(&P.WQKVt[(size_t)(c0 + p2 * 128) * 264 + kb]);
      }
    f32x4 acc[3][2];
#pragma unroll
    for (int p2 = 0; p2 < 3; p2++)
#pragma unroll
      for (int rt = 0; rt < 2; rt++) acc[p2][rt] = (f32x4){0.f,0.f,0.f,0.f};
#pragma unroll
    for (int kt = 0; kt < 8; kt++){
      int kb = kt * 32 + quad * 8;
#pragma unroll
      for (int rt = 0; rt < 2; rt++){
        s16x8 a = *reinterpret_cast<const s16x8*>(&Abf[(rt * 16 + l16) * 264 + kb]);
#pragma unroll
        for (int p2 = 0; p2 < 3; p2++)
          acc[p2][rt] = __builtin_amdgcn_mfma_f32_16x16x32_bf16(a, B[p2][kt], acc[p2][rt], 0, 0, 0);
      }
    }
#pragma unroll
    for (int p2 = 0; p2 < 3; p2++){
      int col = c0 + p2 * 128;
      float bv = P.biasQKV[col];
#pragma unroll
      for (int rt = 0; rt < 2; rt++){
#pragma unroll
        for (int r = 0; r < 4; r++){
          int row = rt * 16 + quad * 4 + r;
          if (row < 25) QKV[row * 388 + col] = acc[p2][rt][r] + bv;
        }
      }
    }
  }
  __syncthreads();

  // SAB scores
  for (int idx = tid; idx < 2500; idx += 512){
    int h = idx / 625;
    int r = idx - h * 625;
    int q = r / 25, k = r - q * 25;
    const float* qp = &QKV[q * 388 + h * 32];
    const float* kp = &QKV[k * 388 + 128 + h * 32];
    float acc = 0.f;
#pragma unroll
    for (int d = 0; d < 32; d += 4){
      float4 a4 = *reinterpret_cast<const float4*>(&qp[d]);
      float4 b4 = *reinterpret_cast<const float4*>(&kp[d]);
      acc = fmaf(a4.x, b4.x, acc); acc = fmaf(a4.y, b4.y, acc);
      acc = fmaf(a4.z, b4.z, acc); acc = fmaf(a4.w, b4.w, acc);
    }
    Ss2[(h * 25 + q) * 26 + k] = acc * 0.0883883476f;
  }
  __syncthreads();
  if (tid < 100){
    int h = tid / 25, k = tid - h * 25;
    float m = -1e30f;
#pragma unroll
    for (int q = 0; q < 25; q++) m = fmaxf(m, Ss2[(h * 25 + q) * 26 + k]);
    float s = 0.f;
#pragma unroll
    for (int q = 0; q < 25; q++){ float e = __expf(Ss2[(h * 25 + q) * 26 + k] - m); Ss2[(h * 25 + q) * 26 + k] = e; s += e; }
    float inv = 1.0f / s;
#pragma unroll
    for (int q = 0; q < 25; q++) Ss2[(h * 25 + q) * 26 + k] *= inv;
  }
  __syncthreads();

  // Ob = Q1 + AV, q-split across tid<256
  if (tid < 256){
    int qh = tid >> 7;
    int c = tid & 127, h = c >> 5;
    int q0 = qh * 13, nq = 13 - qh;
    float acc[13] = {};
    for (int k = 0; k < 25; k++){
      float v = QKV[k * 388 + 256 + c];
      for (int j = 0; j < nq; j++)
        acc[j] = fmaf(Ss2[(h * 25 + q0 + j) * 26 + k], v, acc[j]);
    }
    for (int j = 0; j < nq; j++){
      int q = q0 + j;
      float ob = QKV[q * 388 + c] + acc[j];
      ObF[q * 132 + c] = ob;
      Abf2[q * 136 + c] = f2bf(ob);
    }
  }
  __syncthreads();

  // O1 = Ob + relu(Ob @ Wo1 + bo1)
  {
    int c0 = wave * 16 + l16;
    s16x8 B0[4];
#pragma unroll
    for (int kt = 0; kt < 4; kt++){
      int kb = kt * 32 + quad * 8;
      B0[kt] = *reinterpret_cast<const s16x8*>(&P.Wo1t[(size_t)c0 * 136 + kb]);
    }
    f32x4 a0 = (f32x4){0.f,0.f,0.f,0.f}, a1 = a0;
#pragma unroll
    for (int kt = 0; kt < 4; kt++){
      int kb = kt * 32 + quad * 8;
      s16x8 aA = *reinterpret_cast<const s16x8*>(&Abf2[l16 * 136 + kb]);
      s16x8 aB = *reinterpret_cast<const s16x8*>(&Abf2[(16 + l16) * 136 + kb]);
      a0 = __builtin_amdgcn_mfma_f32_16x16x32_bf16(aA, B0[kt], a0, 0, 0, 0);
      a1 = __builtin_amdgcn_mfma_f32_16x16x32_bf16(aB, B0[kt], a1, 0, 0, 0);
    }
    float bv = P.bo1[c0];
#pragma unroll
    for (int r = 0; r < 4; r++){
      int row0 = quad * 4 + r;
      if (row0 < 25){ float t = a0[r] + bv; O1F[row0 * 132 + c0] = ObF[row0 * 132 + c0] + fmaxf(t, 0.f); }
      int row1 = 16 + quad * 4 + r;
      if (row1 < 25){ float t = a1[r] + bv; O1F[row1 * 132 + c0] = ObF[row1 * 132 + c0] + fmaxf(t, 0.f); }
    }
  }
  __syncthreads();

  // head, split-k
  if (tid < 128){
    float s = 0.f;
    for (int k = 0; k < 25; k++) s += O1F[k * 132 + tid];
    hva[tid] = s;
  }
  __syncthreads();
  {
    int kh = tid >> 7, c = tid & 127;
    if (tid < 256){
      float s = 0.f;
      for (int k = kh * 64; k < kh * 64 + 64; k++)
        s = fmaf(P.S2[k], P.Wq2[k * 128 + c], fmaf(hva[k], P.Wv2[k * 128 + c], s));
      hpart[kh * 128 + c] = s;
    }
    __syncthreads();
    if (tid < 128) hvb[c] = hpart[c] + hpart[128 + c] + P.bq2[c] + 25.f * P.bv2[c];
    __syncthreads();
    if (tid < 256){
      float s = 0.f;
      for (int k = kh * 64; k < kh * 64 + 64; k++) s = fmaf(hvb[k], P.Wo2[k * 128 + c], s);
      hpart[kh * 128 + c] = s;
    }
    __syncthreads();
    if (tid < 128) hva[c] = hvb[c] + fmaxf(hpart[c] + hpart[128 + c] + P.bo2[c], 0.f);
    __syncthreads();
    if (tid < 256){
      float s = 0.f;
      for (int k = kh * 64; k < kh * 64 + 64; k++) s = fmaf(hva[k], P.Wl[k * 128 + c], s);
      hpart[kh * 128 + c] = s;
    }
    __syncthreads();
    if (tid < 128) hvb[c] = hpart[c] + hpart[128 + c] + P.bl[c];
    __syncthreads();
    if (tid < 256){
      float s = 0.f;
      for (int k = kh * 64; k < kh * 64 + 64; k++) s = fmaf(hvb[k], P.Wc1[k * 128 + c], s);
      hpart[kh * 128 + c] = s;
    }
    __syncthreads();
    if (tid < 128) hva[c] = fmaxf(hpart[c] + hpart[128 + c] + P.bc1[c], 0.f);
    __syncthreads();
    if (tid < 128){
      int kh2 = tid >> 6, c2 = tid & 63;
      float s = 0.f;
      for (int k = kh2 * 64; k < kh2 * 64 + 64; k++) s = fmaf(hva[k], P.Wc2[k * 64 + c2], s);
      hpart[kh2 * 64 + c2] = s;
    }
    __syncthreads();
    if (tid < 64) hvb[tid] = fmaxf(hpart[tid] + hpart[64 + tid] + P.bc2[tid], 0.f);
    __syncthreads();
    if (tid < 10){
      float lg = P.bc3[tid];
      for (int k = 0; k < 64; k++) lg = fmaf(hvb[k], P.Wc3[k * 10 + tid], lg);
      P.out[g * 10 + tid] = lg;
    }
  }
}

// ---------------- host ----------------
extern "C" void kernel_launch(void* const* d_in, const int* in_sizes, int n_in,
                              void* d_out, int out_size, void* d_ws, size_t ws_size,
                              hipStream_t stream)
{
  const int*  edge = (const int*)d_in[1];
  const int N = in_sizes[0] / FIN;      // 20000
  const int E = in_sizes[1] / 2;        // 320000
  const int G = N / MAXN;               // 200
  const int* srcp = edge;
  const int* dstp = edge + E;
  float* out = (float*)d_out;           // f32: [logits 200x10 | p1 200x128 | p2 200x128]

  float* w = (float*)d_ws;
  size_t off = 0;
  auto alloc = [&](size_t nfl){ nfl = (nfl + 3) & ~(size_t)3; float* p = w + off; off += nfl; return p; };
  auto allocS = [&](size_t nsh)->short*{ size_t nfl = ((nsh + 1) / 2 + 3) & ~(size_t)3; short* p = (short*)(w + off); off += nfl; return p; };

  float* biasVS  = alloc(356);          // [bv0 | cvec]
  float* biasQKV = alloc(384);          // [bq1 | bk1 | bv1]
  float* cvec = biasVS + 256;

  const int castT[24] = {4,6,7,8,9,10,11,15,23,24,25,26,29,30,31,32,33,34,35,36,37,38,39,40};
  float* wf[41] = {nullptr};
  for (int i = 0; i < 24; i++) wf[castT[i]] = alloc((size_t)in_sizes[castT[i]]);
  wf[13] = biasVS; wf[17] = biasQKV; wf[19] = biasQKV + 128; wf[21] = biasQKV + 256;

  float* Sg  = alloc((size_t)G * 10000);           // scores [g][node][100]
  short* VTg = allocS((size_t)G * 256 * 128);      // V^T bf16 (pads: poison OK, A-side zeros)
  float* Adj = alloc((size_t)G * MAXN * MAXN);     // unnormalized counts
  float* Q0  = alloc(25 * 256);
  short* xaggB = allocS((size_t)N * 256);

  short* W1t   = allocS(128 * 136);
  short* W2t   = allocS(128 * 136);
  short* WVSt  = allocS(356 * 264);     // [Wv0t | Ubart]
  short* WQKVt = allocS(384 * 264);     // [Wq1t | Wk1t | Wv1t]
  short* Wo0t  = allocS(256 * 264);
  short* Wo1t  = allocS(128 * 136);
  short* Ubart = WVSt + (size_t)256 * 264;
  if (off * sizeof(float) > ws_size) return;

  dim3 blk(256);

  // 1. unified prep (inline sniff; casts + transposes + fills Adj=0)
  PrepBatch pb; int ne = 0, blks = 0;
  pb.xptr = d_in[0];
  auto addC = [&](const void* s, float* d, int n){
    pb.src[ne]=s; pb.dst[ne]=d; pb.a[ne]=n; pb.b[ne]=0; pb.blk0[ne]=blks;
    blks += ceil_div(ceil_div(n, 4), 256); ne++; };
  auto addW = [&](const void* s, short* d, int K, int Nn){
    pb.src[ne]=s; pb.dst[ne]=d; pb.a[ne]=K; pb.b[ne]=Nn; pb.blk0[ne]=blks;
    blks += ceil_div(K * Nn, 256); ne++; };
  auto addF = [&](void* d, int n, int mode){
    pb.src[ne]=nullptr; pb.dst[ne]=d; pb.a[ne]=n; pb.b[ne]=mode; pb.blk0[ne]=blks;
    blks += ceil_div(ceil_div(n, 4), 256); ne++; };
  for (int i = 0; i < 24; i++){ int t = castT[i]; addC(d_in[t], wf[t], in_sizes[t]); }
  addC(d_in[13], biasVS, 256);
  addC(d_in[17], biasQKV, 128); addC(d_in[19], biasQKV + 128, 128); addC(d_in[21], biasQKV + 256, 128);
  addW(d_in[3],  W1t, 128, 128);             addW(d_in[5],  W2t, 128, 128);
  addW(d_in[12], WVSt, 256, 256);            addW(d_in[16], WQKVt, 256, 128);
  addW(d_in[18], WQKVt + 128*264, 256, 128); addW(d_in[20], WQKVt + 256*264, 256, 128);
  addW(d_in[14], Wo0t, 256, 256);            addW(d_in[22], Wo1t, 128, 128);
  addF(Adj, G * MAXN * MAXN, -1);
  pb.blk0[ne] = blks; pb.ne = ne;
  prep_all<<<dim3(blks), blk, 0, stream>>>(pb);

  // 2. edge counts (single atomic pass; normalization folded into gcn_all)
  adj_cnt<<<ceil_div(E, 256), blk, 0, stream>>>(srcp, dstp, Adj, E);

  // 3. whole GCN stage per graph (deg/normalize in-block, 8 waves)
  gcn_all<<<dim3(G), dim3(512), 0, stream>>>(d_in[0], Adj, W1t, wf[4], W2t, wf[6],
                                             xaggB, out + 2000, out + 27600);

  // 4. Q0 + Ubar^T + cvec
  ubar_q0<<<dim3(100), blk, 0, stream>>>(wf[7], wf[8], wf[9], wf[10], wf[11], Q0, Ubart, cvec);

  // 5. VdS GEMM: V half transposed bf16 -> VTg; scores -> Sg
  {
    dim3 grid(ceil_div(N, 64), 3);
    gemm_vds<<<grid, blk, 0, stream>>>(xaggB, 256, WVSt, 264, biasVS, VTg, Sg, N, 356);
  }

  // 6. fused tail (8 waves/block, MFMA AV)
  TailParams tp;
  tp.Sg = Sg; tp.VTg = VTg; tp.Q0 = Q0;
  tp.Wo0t = Wo0t; tp.bo0 = wf[15];
  tp.WQKVt = WQKVt; tp.biasQKV = biasQKV;
  tp.Wo1t = Wo1t; tp.bo1 = wf[23];
  tp.S2 = wf[24]; tp.Wq2 = wf[25]; tp.bq2 = wf[26]; tp.Wv2 = wf[29]; tp.bv2 = wf[30];
  tp.Wo2 = wf[31]; tp.bo2 = wf[32]; tp.Wl = wf[33]; tp.bl = wf[34];
  tp.Wc1 = wf[35]; tp.bc1 = wf[36]; tp.Wc2 = wf[37]; tp.bc2 = wf[38];
  tp.Wc3 = wf[39]; tp.bc3 = wf[40];
  tp.out = out;
  tail_all<<<dim3(G), dim3(512), 0, stream>>>(tp);
}